// Round 7
// baseline (14411.664 us; speedup 1.0000x reference)
//
#include <hip/hip_runtime.h>
#include <hip/hip_bf16.h>
#include <math.h>

#define TT 64
#define HH 512
#define VV 30522
#define START_TOK 101
#define NTILE 477      // ceil(30522/64)
#define KCAND 8
#define MARGIN (1.02f / 128.0f)
#define FCB 160        // fc blocks; 3 tiles each

typedef __attribute__((ext_vector_type(8))) short short8v;
typedef __attribute__((ext_vector_type(4))) float f32x4;

__device__ inline short f2bf(float x) {
    union { float f; unsigned u; } v; v.f = x;
    unsigned r = v.u + 0x7FFFu + ((v.u >> 16) & 1u);   // RNE
    return (short)(r >> 16);
}
__device__ inline float bf2f(short s) {
    return __uint_as_float(((unsigned)(unsigned short)s) << 16);
}
__device__ inline unsigned long long packkey(float v, int col) {
    unsigned u = __float_as_uint(v);
    unsigned key = (u & 0x80000000u) ? ~u : (u | 0x80000000u);
    return ((unsigned long long)key << 32) | (unsigned)col;
}
__device__ inline float keyval(unsigned long long k) {
    unsigned hi = (unsigned)(k >> 32);
    unsigned bits = (hi & 0x80000000u) ? (hi ^ 0x80000000u) : ~hi;
    return __uint_as_float(bits);
}

// ws layout (float units):
// h0[2][16384] @ 0 | h1[2][16384] @ 32768 | c0 @ 65536 | c1 @ 81920
// tokbuf int[64*32] @ 98304 | xnorm f32[32] @ 100352 | wmax u32 @ 100384
// flags int[64] @ 100416 | cand u64[32*477*8] @ 100480 (244224 floats)
// w_t bf16 tile-major @ 344704 | h1b16 bf16[64][32][512] @ 8159872

union SMemK {
    struct { float in_lds[32 * 258]; float red[32 * 16 * 8]; float gate[4 * 128]; int tok[32]; } l;
    struct { short a_sh[32 * 512]; float res[32 * 68]; float xnorm[32]; float wmaxv; int cnt[32]; } f;
    struct { unsigned long long red[256]; int list[32]; int lcnt; } a;
};

__global__ void init_k(float* ws, const float* __restrict__ fused) {
    int i = blockIdx.x * blockDim.x + threadIdx.x;
    if (i < 16384) {
        float f = fused[i];
        ws[16384 + i] = f;            // h0 parity-1 (t=0 reads prev = buf1)
        ws[32768 + 16384 + i] = f;    // h1 parity-1
        ws[65536 + i] = 0.f;          // c0
        ws[81920 + i] = 0.f;          // c1
    }
    if (i == 0) ((unsigned*)(ws + 100384))[0] = 0u;      // wmax
    if (i < 64) ((int*)(ws + 100416))[i] = 0;            // step flags (reset every call)
}

__global__ __launch_bounds__(256) void prep_k(const float* __restrict__ fc_w,
                                              short* __restrict__ w_t,
                                              unsigned* __restrict__ wmax) {
    const int tile = blockIdx.x;
    const int c = threadIdx.x >> 2;
    const int seg = threadIdx.x & 3;
    int gcol = tile * 64 + c; if (gcol > VV - 1) gcol = VV - 1;
    const float* wp = fc_w + (size_t)gcol * HH + seg * 128;
    short* tb = w_t + (size_t)tile * 32768 + (c >> 4) * 8192 + (c & 15) * 8;
    float ss = 0.f;
#pragma unroll
    for (int i = 0; i < 16; ++i) {
        float4 x0 = *(const float4*)(wp + i * 8);
        float4 x1 = *(const float4*)(wp + i * 8 + 4);
        ss += x0.x*x0.x + x0.y*x0.y + x0.z*x0.z + x0.w*x0.w
            + x1.x*x1.x + x1.y*x1.y + x1.z*x1.z + x1.w*x1.w;
        short8v s;
        s[0]=f2bf(x0.x); s[1]=f2bf(x0.y); s[2]=f2bf(x0.z); s[3]=f2bf(x0.w);
        s[4]=f2bf(x1.x); s[5]=f2bf(x1.y); s[6]=f2bf(x1.z); s[7]=f2bf(x1.w);
        int k = seg * 128 + i * 8;
        int kt = k >> 5, ksub = (k >> 3) & 3;
        *(short8v*)(tb + kt * 512 + ksub * 128) = s;
    }
    ss += __shfl_xor(ss, 1); ss += __shfl_xor(ss, 2);
    if (seg == 0) atomicMax(wmax, __float_as_uint(sqrtf(ss)));
}

__device__ __forceinline__ void waitflag(int* flags, int t, int want) {
    if (threadIdx.x == 0) {
        int guard = 0;
        while (__hip_atomic_load(&flags[t], __ATOMIC_ACQUIRE, __HIP_MEMORY_SCOPE_AGENT) < want) {
            __builtin_amdgcn_s_sleep(4);
            if (++guard > (1 << 20)) break;   // failsafe: fail loud (wrong), never hang long
        }
    }
    __syncthreads();
    __threadfence();
}

// 4-unit-per-block LSTM phase. mode 0: x = emb[tok] (spins for token);
// mode 1: x = xsrc rows (spins for h0 of this step). h-passes run before the spin.
__device__ void lstm4(SMemK& sm, int t, int mode, int u0,
    const float* __restrict__ xsrc, const float* __restrict__ hprev,
    float* __restrict__ hout, float* __restrict__ cstate,
    const float* __restrict__ w_ih, const float* __restrict__ w_hh,
    const float* __restrict__ b_ih, const float* __restrict__ b_hh,
    const int* __restrict__ tokbuf, int* flags, int want,
    short* __restrict__ h1b16out)
{
    const int tid = threadIdx.x;
    const int j = tid >> 5, b = tid & 31;

    float acc[16];
#pragma unroll
    for (int r = 0; r < 16; ++r) acc[r] = 0.f;
    int rowoff[16];
#pragma unroll
    for (int rl = 0; rl < 16; ++rl) {
        int gt = rl >> 2, ul = rl & 3;
        rowoff[rl] = (gt * 512 + u0 + ul) * 512;
    }

    for (int pp = 0; pp < 4; ++pp) {
        const int p = (pp < 2) ? pp + 2 : pp - 2;   // h-passes first, then x-passes
        if (pp == 2) {
            waitflag(flags, t, want);
            if (mode == 0) {
                if (tid < 32) sm.l.tok[tid] = tokbuf[t * 32 + tid];
                __syncthreads();
            }
        }
        const int koff = (p & 1) * 256;
        for (int i = tid; i < 32 * 128; i += 256) {
            int bb2 = i >> 7, k2 = (i & 127) * 2;
            const float* rp;
            if (p < 2) rp = (mode == 0) ? (xsrc + (size_t)sm.l.tok[bb2] * 512) : (xsrc + bb2 * 512);
            else       rp = hprev + bb2 * 512;
            float2 v = *(const float2*)(rp + koff + k2);
            *(float2*)&sm.l.in_lds[bb2 * 258 + k2] = v;
        }
        __syncthreads();
        const float* wb = (p < 2) ? w_ih : w_hh;
#pragma unroll
        for (int m2 = 0; m2 < 8; ++m2) {
            int kl = j * 32 + m2 * 4;
            float2 x0 = *(const float2*)&sm.l.in_lds[b * 258 + kl];
            float2 x1 = *(const float2*)&sm.l.in_lds[b * 258 + kl + 2];
#pragma unroll
            for (int rl = 0; rl < 16; ++rl) {
                float4 w4 = *(const float4*)(wb + rowoff[rl] + koff + kl);
                acc[rl] += x0.x * w4.x + x0.y * w4.y + x1.x * w4.z + x1.y * w4.w;
            }
        }
        __syncthreads();
    }

#pragma unroll
    for (int rl = 0; rl < 16; ++rl) sm.l.red[(b * 16 + rl) * 8 + j] = acc[rl];
    __syncthreads();

#pragma unroll
    for (int q = 0; q < 2; ++q) {
        int s_ = tid + q * 256;              // 512 (b,rl) sums over 256 threads
        int b2 = s_ >> 4, r2 = s_ & 15;
        float s = 0.f;
#pragma unroll
        for (int jj = 0; jj < 8; ++jj) s += sm.l.red[(b2 * 16 + r2) * 8 + jj];
        int gt = r2 >> 2, ul = r2 & 3;
        int rg = gt * 512 + u0 + ul;
        s += b_ih[rg] + b_hh[rg];
        sm.l.gate[gt * 128 + ul * 32 + b2] = s;
    }
    __syncthreads();

    if (tid < 128) {
        int ul = tid >> 5, b3 = tid & 31;
        float gi = sm.l.gate[0 * 128 + ul * 32 + b3];
        float gf = sm.l.gate[1 * 128 + ul * 32 + b3];
        float gg = sm.l.gate[2 * 128 + ul * 32 + b3];
        float go = sm.l.gate[3 * 128 + ul * 32 + b3];
        float si = 1.f / (1.f + expf(-gi));
        float sf = 1.f / (1.f + expf(-gf));
        float so = 1.f / (1.f + expf(-go));
        float tg = tanhf(gg);
        int u = u0 + ul;
        float cold = cstate[b3 * 512 + u];
        float cn = sf * cold + si * tg;
        cstate[b3 * 512 + u] = cn;
        float h = so * tanhf(cn);
        hout[b3 * 512 + u] = h;
        if (h1b16out) h1b16out[t * 16384 + b3 * 512 + u] = f2bf(h);
    }
    __syncthreads();
    if (tid == 0) { __threadfence(); atomicAdd(&flags[t], 1); }
}

// One dispatch per timestep: resolver(32) | lstm0(128) | lstm1(128) | fc(160x3 tiles).
// 448 blocks, all co-resident (>=2 blocks/CU x 256 CUs = 512) -> progress guaranteed.
__global__ __launch_bounds__(256, 2) void step_k(
    int t,
    const float* __restrict__ emb, const int* __restrict__ target, const int* __restrict__ tfm,
    const float* __restrict__ h0prev, float* __restrict__ h0cur, float* __restrict__ c0,
    const float* __restrict__ w_ih0, const float* __restrict__ w_hh0,
    const float* __restrict__ b_ih0, const float* __restrict__ b_hh0,
    const float* __restrict__ h1prev, float* __restrict__ h1cur, float* __restrict__ c1,
    const float* __restrict__ w_ih1, const float* __restrict__ w_hh1,
    const float* __restrict__ b_ih1, const float* __restrict__ b_hh1,
    short* __restrict__ h1b16, const short* __restrict__ w_t,
    const float* __restrict__ fc_w, const float* __restrict__ fc_b,
    unsigned long long* __restrict__ cand, float* __restrict__ xnorm_g,
    const unsigned* __restrict__ wmax,
    int* __restrict__ tokbuf, int* __restrict__ flags)
{
    __shared__ SMemK sm;
    const int tid = threadIdx.x;
    const int bid = blockIdx.x;

    if (bid < 32) {
        // ---- resolver: token for step t (teacher, or exact rescored argmax of t-1) ----
        const int r = bid;
        int tok = START_TOK;
        if (t > 0) {
            if (tfm[t - 1] > 0) {
                tok = target[r * TT + t];
            } else {
                const int n = NTILE * KCAND;
                const unsigned long long* cp = cand + (size_t)r * n;
                unsigned long long m = 0ull;
                for (int i = tid; i < n; i += 256) { unsigned long long k = cp[i]; m = (k > m) ? k : m; }
                sm.a.red[tid] = m; __syncthreads();
                for (int s = 128; s > 0; s >>= 1) {
                    if (tid < s) { unsigned long long o = sm.a.red[tid + s]; if (o > sm.a.red[tid]) sm.a.red[tid] = o; }
                    __syncthreads();
                }
                float Mv = keyval(sm.a.red[0]);
                float thr = Mv - xnorm_g[r] * __uint_as_float(*wmax) * MARGIN;
                if (tid == 0) sm.a.lcnt = 0;
                __syncthreads();
                for (int i = tid; i < n; i += 256) {
                    unsigned long long k = cp[i];
                    if (!k) continue;
                    if (keyval(k) >= thr) {
                        int idx = atomicAdd(&sm.a.lcnt, 1);
                        if (idx < 32) sm.a.list[idx] = (int)(k & 0xFFFFFFFFull);
                    }
                }
                __syncthreads();
                int nc = sm.a.lcnt < 32 ? sm.a.lcnt : 32;
                if (tid < 64) {
                    float bv = -__builtin_inff(); int bc = 0x7FFFFFFF;
                    for (int jc = 0; jc < nc; ++jc) {
                        int col = sm.a.list[jc];
                        const float* wp = fc_w + (size_t)col * HH + tid * 8;
                        const float* xp = h1prev + r * 512 + tid * 8;
                        float4 a0 = *(const float4*)wp, a1 = *(const float4*)(wp + 4);
                        float4 b0 = *(const float4*)xp, b1 = *(const float4*)(xp + 4);
                        float s = a0.x*b0.x + a0.y*b0.y + a0.z*b0.z + a0.w*b0.w
                                + a1.x*b1.x + a1.y*b1.y + a1.z*b1.z + a1.w*b1.w;
#pragma unroll
                        for (int d = 1; d < 64; d <<= 1) s += __shfl_xor(s, d);
                        s += fc_b[col];
                        if (s > bv || (s == bv && col < bc)) { bv = s; bc = col; }
                    }
                    if (tid == 0) sm.a.lcnt = bc;
                }
                __syncthreads();
                tok = sm.a.lcnt;
            }
        }
        if (tid == 0) {
            tokbuf[t * 32 + r] = tok;
            __threadfence();
            atomicAdd(&flags[t], 1);    // -> 32
        }
        return;
    }

    if (bid < 160) {   // ---- lstm0: 128 blocks x 4 units; spins for token (>=32) ----
        lstm4(sm, t, 0, (bid - 32) * 4, emb, h0prev, h0cur, c0,
              w_ih0, w_hh0, b_ih0, b_hh0, tokbuf, flags, 32, nullptr);
        return;        // bump -> toward 160
    }

    if (bid < 288) {   // ---- lstm1: 128 blocks x 4 units; spins for h0 (>=160) ----
        lstm4(sm, t, 1, (bid - 160) * 4, h0cur, h1prev, h1cur, c1,
              w_ih1, w_hh1, b_ih1, b_hh1, tokbuf, flags, 160, h1b16);
        return;        // bump -> toward 288
    }

    // ---- fc: FCB blocks x 3 tiles; candidates only, non-TF steps ----
    const int blkL = bid - 288;
    const bool emit = (t < TT - 1) && (tfm[t] == 0);
    if (!emit) return;
    const int w = tid >> 6, l = tid & 63;
    const float NEG_INF = -__builtin_inff();

    // prefetch tile0 B-fragments before the spin (independent of h1)
    const short* bpl0 = w_t + (size_t)blkL * 32768 + w * 8192 + l * 8;
    short8v pre[8];
#pragma unroll
    for (int i = 0; i < 8; ++i) pre[i] = *(const short8v*)(bpl0 + i * 512);

    waitflag(flags, t, 288);   // wait for all h1 (and h1b16) writes

    // stage A from h1b16 (bit-identical to f2bf(h1)) + bf16-derived row norms
    {
        int row = tid >> 3, seg = tid & 7;
        const short* hp = h1b16 + t * 16384 + row * 512 + seg * 64;
        float ss = 0.f;
#pragma unroll
        for (int c = 0; c < 8; ++c) {
            short8v v = *(const short8v*)(hp + c * 8);
            int kbase = seg * 64 + c * 8;
            int off = (row * 1024 + kbase * 2) ^ ((row & 7) << 4);
            *(short8v*)((char*)sm.f.a_sh + off) = v;
#pragma unroll
            for (int e = 0; e < 8; ++e) { float f = bf2f(v[e]); ss += f * f; }
        }
        ss += __shfl_xor(ss, 1); ss += __shfl_xor(ss, 2); ss += __shfl_xor(ss, 4);
        if (seg == 0) sm.f.xnorm[row] = sqrtf(ss);
        if (tid == 0) sm.f.wmaxv = __uint_as_float(*wmax);
    }
    __syncthreads();
    if (bid == 288 && tid < 32) xnorm_g[tid] = sm.f.xnorm[tid];

    const int r0 = (l & 15), r1 = (l & 15) + 16;
    for (int ti = 0; ti < 3; ++ti) {
        const int tile = blkL + ti * FCB;
        if (tile >= NTILE) break;
        const int n0 = tile * 64 + w * 16;
        int bcol = n0 + (l & 15); if (bcol > VV - 1) bcol = VV - 1;
        const short* bpl = w_t + (size_t)tile * 32768 + w * 8192 + l * 8;
        f32x4 acc0 = {0.f,0.f,0.f,0.f}, acc1 = {0.f,0.f,0.f,0.f};
        short8v bf[8];
        if (ti == 0) {
#pragma unroll
            for (int i = 0; i < 8; ++i) bf[i] = pre[i];
        } else {
#pragma unroll
            for (int i = 0; i < 8; ++i) bf[i] = *(const short8v*)(bpl + i * 512);
        }
#pragma unroll
        for (int kt = 0; kt < 16; ++kt) {
            short8v bfrag = bf[kt & 7];
            if (kt < 8) bf[kt & 7] = *(const short8v*)(bpl + (kt + 8) * 512);
            int k2 = (kt * 32 + (l >> 4) * 8) * 2;
            short8v a0 = *(const short8v*)((char*)sm.f.a_sh + ((r0 * 1024 + k2) ^ ((r0 & 7) << 4)));
            short8v a1 = *(const short8v*)((char*)sm.f.a_sh + ((r1 * 1024 + k2) ^ ((r1 & 7) << 4)));
            acc0 = __builtin_amdgcn_mfma_f32_16x16x32_bf16(a0, bfrag, acc0, 0, 0, 0);
            acc1 = __builtin_amdgcn_mfma_f32_16x16x32_bf16(a1, bfrag, acc1, 0, 0, 0);
        }

        __syncthreads();   // previous tile's res/cnt consumers done
        {
            float bias = fc_b[bcol];
            bool oob = (n0 + (l & 15)) >= VV;
            int cl = w * 16 + (l & 15);
#pragma unroll
            for (int r = 0; r < 4; ++r) {
                int m = (l >> 4) * 4 + r;
                sm.f.res[m * 68 + cl]        = oob ? NEG_INF : acc0[r] + bias;
                sm.f.res[(m + 16) * 68 + cl] = oob ? NEG_INF : acc1[r] + bias;
            }
        }
        __syncthreads();

        {
            int row = tid >> 3, sub = tid & 7;
            float bv = NEG_INF; int bc = 0x7FFFFFFF;
            for (int c = 0; c < 8; ++c) {
                float v = sm.f.res[row * 68 + sub * 8 + c];
                if (v > bv) { bv = v; bc = tile * 64 + sub * 8 + c; }
            }
#pragma unroll
            for (int d = 1; d < 8; d <<= 1) {
                float ov = __shfl_xor(bv, d);
                int oc = __shfl_xor(bc, d);
                if (ov > bv || (ov == bv && oc < bc)) { bv = ov; bc = oc; }
            }
            unsigned long long* slotp = cand + ((size_t)row * NTILE + tile) * KCAND;
            if (sub == 0) { slotp[0] = packkey(bv, bc); sm.f.cnt[row] = 1; }
            __syncthreads();
            float cthr = bv - sm.f.xnorm[row] * sm.f.wmaxv * MARGIN;
            for (int c = 0; c < 8; ++c) {
                float v = sm.f.res[row * 68 + sub * 8 + c];
                int col = tile * 64 + sub * 8 + c;
                if (v >= cthr && col != bc) {
                    int idx = atomicAdd(&sm.f.cnt[row], 1);
                    if (idx < KCAND) slotp[idx] = packkey(v, col);
                }
            }
            __syncthreads();
            if (sub == 0) {
                int n = sm.f.cnt[row]; if (n > KCAND) n = KCAND;
                for (int k = n; k < KCAND; ++k) slotp[k] = 0ull;
            }
            __syncthreads();
        }
    }
}

// Batched logits GEMM: [2048 x 30522] = h1b16 x w_t^T + fc_b, written once.
__global__ __launch_bounds__(256) void logits_all(
    const short* __restrict__ h1b16,
    const short* __restrict__ w_t,
    const float* __restrict__ fc_b,
    float* __restrict__ out)
{
    __shared__ short a_sh[32 * 512];
    __shared__ float res_sh[32 * 68];
    const int tid = threadIdx.x;
    const int blk = blockIdx.x;
    const int tg  = blockIdx.y;
    const float NEG_INF = -__builtin_inff();

    const int w = tid >> 6, l = tid & 63;
    const int n0 = blk * 64 + w * 16;
    int bcol = n0 + (l & 15); if (bcol > VV - 1) bcol = VV - 1;
    const bool oob = (n0 + (l & 15)) >= VV;
    const float bias = fc_b[bcol];
    const short* bpl = w_t + (size_t)blk * 32768 + w * 8192 + l * 8;
    short8v bfr[16];
#pragma unroll
    for (int kt = 0; kt < 16; ++kt) bfr[kt] = *(const short8v*)(bpl + kt * 512);

    const int r0 = (l & 15), r1 = (l & 15) + 16;
    const int srow = tid >> 3, sseg = tid & 7;

    for (int ts = 0; ts < 8; ++ts) {
        const int t = tg * 8 + ts;
        const short* hp = h1b16 + t * 16384 + srow * 512 + sseg * 64;
#pragma unroll
        for (int c = 0; c < 8; ++c) {
            short8v v = *(const short8v*)(hp + c * 8);
            int k = sseg * 64 + c * 8;
            int off = (srow * 1024 + k * 2) ^ ((srow & 7) << 4);
            *(short8v*)((char*)a_sh + off) = v;
        }
        __syncthreads();

        f32x4 acc0 = {0.f,0.f,0.f,0.f}, acc1 = {0.f,0.f,0.f,0.f};
#pragma unroll
        for (int kt = 0; kt < 16; ++kt) {
            int k2 = (kt * 32 + (l >> 4) * 8) * 2;
            short8v a0 = *(const short8v*)((char*)a_sh + ((r0 * 1024 + k2) ^ ((r0 & 7) << 4)));
            short8v a1 = *(const short8v*)((char*)a_sh + ((r1 * 1024 + k2) ^ ((r1 & 7) << 4)));
            acc0 = __builtin_amdgcn_mfma_f32_16x16x32_bf16(a0, bfr[kt], acc0, 0, 0, 0);
            acc1 = __builtin_amdgcn_mfma_f32_16x16x32_bf16(a1, bfr[kt], acc1, 0, 0, 0);
        }
        {
            int cl = w * 16 + (l & 15);
#pragma unroll
            for (int r = 0; r < 4; ++r) {
                int m = (l >> 4) * 4 + r;
                res_sh[m * 68 + cl]        = oob ? NEG_INF : acc0[r] + bias;
                res_sh[(m + 16) * 68 + cl] = oob ? NEG_INF : acc1[r] + bias;
            }
        }
        __syncthreads();
        for (int i = tid; i < 32 * 64; i += 256) {
            int m = i >> 6, cl = i & 63;
            int col = blk * 64 + cl;
            if (col < VV) out[((size_t)m * TT + t) * VV + col] = res_sh[m * 68 + cl];
        }
        __syncthreads();
    }
}

extern "C" void kernel_launch(void* const* d_in, const int* in_sizes, int n_in,
                              void* d_out, int out_size, void* d_ws, size_t ws_size,
                              hipStream_t stream) {
    const float* fused  = (const float*)d_in[0];
    const int*   target = (const int*)d_in[1];
    const int*   tfm    = (const int*)d_in[2];
    const float* emb    = (const float*)d_in[3];
    const float* w_ih0  = (const float*)d_in[4];
    const float* w_hh0  = (const float*)d_in[5];
    const float* b_ih0  = (const float*)d_in[6];
    const float* b_hh0  = (const float*)d_in[7];
    const float* w_ih1  = (const float*)d_in[8];
    const float* w_hh1  = (const float*)d_in[9];
    const float* b_ih1  = (const float*)d_in[10];
    const float* b_hh1  = (const float*)d_in[11];
    const float* fc_w   = (const float*)d_in[12];
    const float* fc_b   = (const float*)d_in[13];
    float* out = (float*)d_out;

    float* ws = (float*)d_ws;
    float* h0buf = ws;
    float* h1buf = ws + 32768;
    float* c0 = ws + 65536;
    float* c1 = ws + 81920;
    int* tokbuf = (int*)(ws + 98304);
    float* xnorm = ws + 100352;
    unsigned* wmax = (unsigned*)(ws + 100384);
    int* flags = (int*)(ws + 100416);
    unsigned long long* cand = (unsigned long long*)(ws + 100480);
    short* w_t = (short*)(ws + 344704);
    short* h1b16 = (short*)(ws + 8159872);

    init_k<<<64, 256, 0, stream>>>(ws, fused);
    prep_k<<<NTILE, 256, 0, stream>>>(fc_w, w_t, wmax);

    for (int t = 0; t < TT; ++t) {
        const float* h0prev = h0buf + ((t + 1) & 1) * 16384;
        float*       h0cur  = h0buf + (t & 1) * 16384;
        const float* h1prev = h1buf + ((t + 1) & 1) * 16384;
        float*       h1cur  = h1buf + (t & 1) * 16384;

        step_k<<<288 + FCB, 256, 0, stream>>>(t, emb, target, tfm,
                                              h0prev, h0cur, c0, w_ih0, w_hh0, b_ih0, b_hh0,
                                              h1prev, h1cur, c1, w_ih1, w_hh1, b_ih1, b_hh1,
                                              h1b16, w_t, fc_w, fc_b, cand, xnorm, wmax,
                                              tokbuf, flags);
    }
    logits_all<<<dim3(NTILE, 8), 256, 0, stream>>>(h1b16, w_t, fc_b, out);
}

// Round 10
// 5070.390 us; speedup vs baseline: 2.8423x; 2.8423x over previous
//
#include <hip/hip_runtime.h>
#include <hip/hip_bf16.h>
#include <math.h>

#define TT 64
#define HH 512
#define VV 30522
#define START_TOK 101
#define NTILE 477      // ceil(30522/64)
#define KCAND 8

typedef __attribute__((ext_vector_type(8))) short short8v;
typedef __attribute__((ext_vector_type(4))) float f32x4;

__device__ inline short f2bf(float x) {
    union { float f; unsigned u; } v; v.f = x;
    unsigned r = v.u + 0x7FFFu + ((v.u >> 16) & 1u);   // RNE
    return (short)(r >> 16);
}
__device__ inline unsigned long long packkey(float v, int col) {
    unsigned u = __float_as_uint(v);
    unsigned key = (u & 0x80000000u) ? ~u : (u | 0x80000000u);
    return ((unsigned long long)key << 32) | (unsigned)col;
}
__device__ inline float keyval(unsigned long long k) {
    unsigned hi = (unsigned)(k >> 32);
    unsigned bits = (hi & 0x80000000u) ? (hi ^ 0x80000000u) : ~hi;
    return __uint_as_float(bits);
}

// ws layout (float units):
// h0[2][16384] @ 0 | h1[2][16384] @ 32768 | c0 @ 65536 | c1 @ 81920
// tokbuf int[64*32] @ 98304 | xnorm f32[32] @ 100352 | wmax u32 @ 100384
// cand u64[32*477*8] @ 100416 (244224 floats, ends 344640)
// w_hi bf16[30522*512] @ 344640 (7813632 floats, ends 8158272)
// h1b16 bf16[64][32][512] @ 8158272 (524288 floats) -> total ~34.7 MB

__global__ void init_k(float* ws, const float* __restrict__ fused) {
    int i = blockIdx.x * blockDim.x + threadIdx.x;
    if (i < 16384) {
        float f = fused[i];
        ws[16384 + i] = f;            // h0 parity-1 (t=0 reads prev = buf1)
        ws[32768 + 16384 + i] = f;    // h1 parity-1
        ws[65536 + i] = 0.f;          // c0
        ws[81920 + i] = 0.f;          // c1
    }
    if (i == 0) ((unsigned*)(ws + 100384))[0] = 0u;      // wmax (reset every call)
}

// fc_w fp32 -> bf16 (RNE, row-major) + global max column L2-norm
__global__ __launch_bounds__(256) void prep_k(const float* __restrict__ fc_w,
                                              short* __restrict__ w_hi,
                                              unsigned* __restrict__ wmax) {
    int r = blockIdx.x * 64 + (threadIdx.x >> 2);
    int seg = threadIdx.x & 3;
    if (r >= VV) return;
    const float* wp = fc_w + (size_t)r * HH + seg * 128;
    short* op = w_hi + (size_t)r * HH + seg * 128;
    float ss = 0.f;
#pragma unroll
    for (int c = 0; c < 16; ++c) {
        float4 x0 = *(const float4*)(wp + c * 8);
        float4 x1 = *(const float4*)(wp + c * 8 + 4);
        ss += x0.x*x0.x + x0.y*x0.y + x0.z*x0.z + x0.w*x0.w
            + x1.x*x1.x + x1.y*x1.y + x1.z*x1.z + x1.w*x1.w;
        short8v s;
        s[0]=f2bf(x0.x); s[1]=f2bf(x0.y); s[2]=f2bf(x0.z); s[3]=f2bf(x0.w);
        s[4]=f2bf(x1.x); s[5]=f2bf(x1.y); s[6]=f2bf(x1.z); s[7]=f2bf(x1.w);
        *(short8v*)(op + c * 8) = s;
    }
    ss += __shfl_xor(ss, 1); ss += __shfl_xor(ss, 2);
    if (seg == 0) atomicMax(wmax, __float_as_uint(sqrtf(ss)));
}

// One LSTM layer, one timestep (R2-proven). mode 0: x = emb[tokbuf]; mode 1: x = xsrc rows.
// h1b16out (nullable): bf16 archive of this step's h (for the batched logits GEMM).
__global__ __launch_bounds__(256) void lstm_step(
    int t, int mode,
    const float* __restrict__ xsrc,
    const int* __restrict__ tokbuf,
    const float* __restrict__ hprev,
    float* __restrict__ hout,
    float* __restrict__ cstate,
    const float* __restrict__ w_ih,
    const float* __restrict__ w_hh,
    const float* __restrict__ b_ih,
    const float* __restrict__ b_hh,
    short* __restrict__ h1b16out)
{
    __shared__ float in_lds[32 * 258];
    __shared__ float red[32 * 64];
    __shared__ float gate[4 * 64];
    __shared__ int tok_lds[32];

    const int tid = threadIdx.x;
    const int j = tid >> 5, b = tid & 31;
    const int u0 = blockIdx.x * 2;

    if (mode == 0 && tid < 32)
        tok_lds[tid] = (t == 0) ? START_TOK : tokbuf[t * 32 + tid];
    __syncthreads();

    float acc[8];
#pragma unroll
    for (int r = 0; r < 8; ++r) acc[r] = 0.f;
    int rowoff[8];
#pragma unroll
    for (int rl = 0; rl < 8; ++rl) {
        int gt = rl >> 1, ul = rl & 1;
        rowoff[rl] = (gt * 512 + u0 + ul) * 512;
    }

    for (int p = 0; p < 4; ++p) {
        const int koff = (p & 1) * 256;
        for (int i = tid; i < 32 * 128; i += 256) {
            int bb2 = i >> 7, k2 = (i & 127) * 2;
            const float* rp;
            if (p < 2) rp = (mode == 0) ? (xsrc + (size_t)tok_lds[bb2] * 512) : (xsrc + bb2 * 512);
            else       rp = hprev + bb2 * 512;
            float2 v = *(const float2*)(rp + koff + k2);
            *(float2*)&in_lds[bb2 * 258 + k2] = v;
        }
        __syncthreads();
        const float* wb = (p < 2) ? w_ih : w_hh;
#pragma unroll
        for (int m2 = 0; m2 < 8; ++m2) {
            int kl = j * 32 + m2 * 4;
            float2 x0 = *(const float2*)&in_lds[b * 258 + kl];
            float2 x1 = *(const float2*)&in_lds[b * 258 + kl + 2];
#pragma unroll
            for (int rl = 0; rl < 8; ++rl) {
                float4 w4 = *(const float4*)(wb + rowoff[rl] + koff + kl);
                acc[rl] += x0.x * w4.x + x0.y * w4.y + x1.x * w4.z + x1.y * w4.w;
            }
        }
        __syncthreads();
    }

#pragma unroll
    for (int rl = 0; rl < 8; ++rl) red[(b * 8 + rl) * 8 + j] = acc[rl];
    __syncthreads();

    {
        int b2 = tid >> 3, r2 = tid & 7;
        float s = 0.f;
#pragma unroll
        for (int jj = 0; jj < 8; ++jj) s += red[(b2 * 8 + r2) * 8 + jj];
        int gt = r2 >> 1, ul = r2 & 1;
        int rg = gt * 512 + u0 + ul;
        s += b_ih[rg] + b_hh[rg];
        gate[gt * 64 + ul * 32 + b2] = s;
    }
    __syncthreads();

    if (tid < 64) {
        int ul = tid >> 5, b3 = tid & 31;
        float gi = gate[0 * 64 + tid];
        float gf = gate[1 * 64 + tid];
        float gg = gate[2 * 64 + tid];
        float go = gate[3 * 64 + tid];
        float si = 1.f / (1.f + expf(-gi));
        float sf = 1.f / (1.f + expf(-gf));
        float so = 1.f / (1.f + expf(-go));
        float tg = tanhf(gg);
        int u = u0 + ul;
        float cold = cstate[b3 * 512 + u];
        float cn = sf * cold + si * tg;
        cstate[b3 * 512 + u] = cn;
        float h = so * tanhf(cn);
        hout[b3 * 512 + u] = h;
        if (h1b16out) h1b16out[b3 * 512 + u] = f2bf(h);
    }
}

// Candidate-only FC (non-TF steps): bf16 MFMA + margin candidates. No logit writes.
__global__ __launch_bounds__(256) void fcarg(
    int t,
    const int* __restrict__ tfm,
    const float* __restrict__ h1,     // [32][512] fp32
    const short* __restrict__ w_hi,   // [30522][512] bf16 row-major
    const float* __restrict__ fc_b,
    unsigned long long* __restrict__ cand,
    float* __restrict__ xnorm_g,
    const unsigned* __restrict__ wmax)
{
    if (tfm[t] > 0) return;   // teacher-forced: argmax not needed

    __shared__ short a_sh[32 * 512];
    __shared__ float res_sh[32 * 68];
    __shared__ float xnorm_sh[32];
    __shared__ float wmax_sh;
    __shared__ int cnt_sh[32];

    const int tid = threadIdx.x;
    const int blk = blockIdx.x;
    const float NEG_INF = -__builtin_inff();

    // Phase 1: h1 -> bf16 LDS (swizzled) + row norms
    {
        int row = tid >> 3, seg = tid & 7;
        const float* hp = h1 + row * 512 + seg * 64;
        float ss = 0.f;
#pragma unroll
        for (int c = 0; c < 8; ++c) {
            float4 x0 = *(const float4*)(hp + c * 8);
            float4 x1 = *(const float4*)(hp + c * 8 + 4);
            ss += x0.x*x0.x + x0.y*x0.y + x0.z*x0.z + x0.w*x0.w
                + x1.x*x1.x + x1.y*x1.y + x1.z*x1.z + x1.w*x1.w;
            short8v s;
            s[0]=f2bf(x0.x); s[1]=f2bf(x0.y); s[2]=f2bf(x0.z); s[3]=f2bf(x0.w);
            s[4]=f2bf(x1.x); s[5]=f2bf(x1.y); s[6]=f2bf(x1.z); s[7]=f2bf(x1.w);
            int kbase = seg * 64 + c * 8;
            int off = (row * 1024 + kbase * 2) ^ ((row & 7) << 4);
            *(short8v*)((char*)a_sh + off) = s;
        }
        ss += __shfl_xor(ss, 1); ss += __shfl_xor(ss, 2); ss += __shfl_xor(ss, 4);
        if (seg == 0) xnorm_sh[row] = sqrtf(ss);
        if (tid == 0) wmax_sh = __uint_as_float(*wmax);
    }
    __syncthreads();
    if (blk == 0 && tid < 32) xnorm_g[tid] = xnorm_sh[tid];

    // Phase 2: MFMA (row-major B fragment loads, R2-proven)
    const int w = tid >> 6, l = tid & 63;
    const int n0 = blk * 64 + w * 16;
    int bcol = n0 + (l & 15); if (bcol > VV - 1) bcol = VV - 1;
    const short* bp = w_hi + (size_t)bcol * HH + ((l >> 4) * 8);
    const int r0 = (l & 15), r1 = (l & 15) + 16;
    f32x4 acc0 = {0.f, 0.f, 0.f, 0.f}, acc1 = {0.f, 0.f, 0.f, 0.f};
#pragma unroll
    for (int kt = 0; kt < 16; ++kt) {
        int k2 = (kt * 32 + (l >> 4) * 8) * 2;
        short8v bfrag = *(const short8v*)(bp + kt * 32);
        short8v a0 = *(const short8v*)((char*)a_sh + ((r0 * 1024 + k2) ^ ((r0 & 7) << 4)));
        short8v a1 = *(const short8v*)((char*)a_sh + ((r1 * 1024 + k2) ^ ((r1 & 7) << 4)));
        acc0 = __builtin_amdgcn_mfma_f32_16x16x32_bf16(a0, bfrag, acc0, 0, 0, 0);
        acc1 = __builtin_amdgcn_mfma_f32_16x16x32_bf16(a1, bfrag, acc1, 0, 0, 0);
    }

    // Phase 3: bias + res LDS
    {
        float bias = fc_b[bcol];
        bool oob = (n0 + (l & 15)) >= VV;
        int cl = w * 16 + (l & 15);
#pragma unroll
        for (int r = 0; r < 4; ++r) {
            int m = (l >> 4) * 4 + r;
            res_sh[m * 68 + cl]        = oob ? NEG_INF : acc0[r] + bias;
            res_sh[(m + 16) * 68 + cl] = oob ? NEG_INF : acc1[r] + bias;
        }
    }
    __syncthreads();

    // Phase 4: per-row block top + margin candidates
    {
        int row = tid >> 3, sub = tid & 7;
        float bv = NEG_INF; int bc = 0x7FFFFFFF;
        for (int c = 0; c < 8; ++c) {
            float v = res_sh[row * 68 + sub * 8 + c];
            if (v > bv) { bv = v; bc = blk * 64 + sub * 8 + c; }
        }
#pragma unroll
        for (int d = 1; d < 8; d <<= 1) {
            float ov = __shfl_xor(bv, d);
            int oc = __shfl_xor(bc, d);
            if (ov > bv || (ov == bv && oc < bc)) { bv = ov; bc = oc; }
        }
        unsigned long long* slotp = cand + ((size_t)row * NTILE + blk) * KCAND;
        if (sub == 0) { slotp[0] = packkey(bv, bc); cnt_sh[row] = 1; }
        __syncthreads();
        float cthr = bv - xnorm_sh[row] * wmax_sh * (1.0f / 128.0f);
        for (int c = 0; c < 8; ++c) {
            float v = res_sh[row * 68 + sub * 8 + c];
            int col = blk * 64 + sub * 8 + c;
            if (v >= cthr && col != bc) {
                int idx = atomicAdd(&cnt_sh[row], 1);
                if (idx < KCAND) slotp[idx] = packkey(v, col);
            }
        }
        __syncthreads();
        if (sub == 0) {
            int n = cnt_sh[row]; if (n > KCAND) n = KCAND;
            for (int k = n; k < KCAND; ++k) slotp[k] = 0ull;
        }
    }
}

// Global candidate scan + exact fp32 rescore -> token for step t+1 (R2-proven)
__global__ __launch_bounds__(256) void argmax_k(
    int t,
    const int* __restrict__ target,
    const int* __restrict__ tfm,
    const unsigned long long* __restrict__ cand,
    const float* __restrict__ h1,
    const float* __restrict__ fc_w,
    const float* __restrict__ fc_b,
    const float* __restrict__ xnorm,
    const unsigned* __restrict__ wmax,
    int* __restrict__ tokbuf)
{
    const int r = blockIdx.x, tid = threadIdx.x;
    if (tfm[t] > 0) {
        if (tid == 0) tokbuf[(t + 1) * 32 + r] = target[r * TT + t + 1];
        return;
    }
    __shared__ unsigned long long red[256];
    __shared__ int list[32];
    __shared__ int lcnt;
    const int n = NTILE * KCAND;
    const unsigned long long* cp = cand + (size_t)r * n;

    unsigned long long m = 0ull;
    for (int i = tid; i < n; i += 256) { unsigned long long k = cp[i]; m = (k > m) ? k : m; }
    red[tid] = m; __syncthreads();
    for (int s = 128; s > 0; s >>= 1) {
        if (tid < s) { unsigned long long o = red[tid + s]; if (o > red[tid]) red[tid] = o; }
        __syncthreads();
    }
    float Mv = keyval(red[0]);
    float thr = Mv - xnorm[r] * __uint_as_float(*wmax) * (1.0f / 128.0f);
    if (tid == 0) lcnt = 0;
    __syncthreads();
    for (int i = tid; i < n; i += 256) {
        unsigned long long k = cp[i];
        if (!k) continue;
        float v = keyval(k);
        if (v >= thr) {
            int idx = atomicAdd(&lcnt, 1);
            if (idx < 32) list[idx] = (int)(k & 0xFFFFFFFFull);
        }
    }
    __syncthreads();
    int nc = lcnt < 32 ? lcnt : 32;

    if (tid < 64) {
        float bv = -__builtin_inff(); int bc = 0x7FFFFFFF;
        for (int jc = 0; jc < nc; ++jc) {
            int col = list[jc];
            const float* wp = fc_w + (size_t)col * HH + tid * 8;
            const float* xp = h1 + r * 512 + tid * 8;
            float4 a0 = *(const float4*)wp, a1 = *(const float4*)(wp + 4);
            float4 b0 = *(const float4*)xp, b1 = *(const float4*)(xp + 4);
            float s = a0.x*b0.x + a0.y*b0.y + a0.z*b0.z + a0.w*b0.w
                    + a1.x*b1.x + a1.y*b1.y + a1.z*b1.z + a1.w*b1.w;
#pragma unroll
            for (int d = 1; d < 64; d <<= 1) s += __shfl_xor(s, d);
            s += fc_b[col];
            if (s > bv || (s == bv && col < bc)) { bv = s; bc = col; }
        }
        if (tid == 0) tokbuf[(t + 1) * 32 + r] = bc;
    }
}

// Batched logits GEMM: [2048 x 30522] = h1b16 x w_hi^T + fc_b, written once.
__global__ __launch_bounds__(256) void logits_all(
    const short* __restrict__ h1b16,   // [64][32][512] bf16
    const short* __restrict__ w_hi,    // [30522][512] bf16 row-major
    const float* __restrict__ fc_b,
    float* __restrict__ out)
{
    __shared__ short a_sh[32 * 512];
    __shared__ float res_sh[32 * 68];
    const int tid = threadIdx.x;
    const int blk = blockIdx.x;        // col tile
    const int tg  = blockIdx.y;        // 8 timesteps per group
    const float NEG_INF = -__builtin_inff();

    const int w = tid >> 6, l = tid & 63;
    const int n0 = blk * 64 + w * 16;
    int bcol = n0 + (l & 15); if (bcol > VV - 1) bcol = VV - 1;
    const bool oob = (n0 + (l & 15)) >= VV;
    const float bias = fc_b[bcol];
    const short* bp = w_hi + (size_t)bcol * HH + ((l >> 4) * 8);
    short8v bfr[16];
#pragma unroll
    for (int kt = 0; kt < 16; ++kt) bfr[kt] = *(const short8v*)(bp + kt * 32);

    const int r0 = (l & 15), r1 = (l & 15) + 16;
    const int srow = tid >> 3, sseg = tid & 7;

    for (int ts = 0; ts < 8; ++ts) {
        const int t = tg * 8 + ts;
        const short* hp = h1b16 + t * 16384 + srow * 512 + sseg * 64;
#pragma unroll
        for (int c = 0; c < 8; ++c) {
            short8v v = *(const short8v*)(hp + c * 8);
            int k = sseg * 64 + c * 8;
            int off = (srow * 1024 + k * 2) ^ ((srow & 7) << 4);
            *(short8v*)((char*)a_sh + off) = v;
        }
        __syncthreads();

        f32x4 acc0 = {0.f,0.f,0.f,0.f}, acc1 = {0.f,0.f,0.f,0.f};
#pragma unroll
        for (int kt = 0; kt < 16; ++kt) {
            int k2 = (kt * 32 + (l >> 4) * 8) * 2;
            short8v a0 = *(const short8v*)((char*)a_sh + ((r0 * 1024 + k2) ^ ((r0 & 7) << 4)));
            short8v a1 = *(const short8v*)((char*)a_sh + ((r1 * 1024 + k2) ^ ((r1 & 7) << 4)));
            acc0 = __builtin_amdgcn_mfma_f32_16x16x32_bf16(a0, bfr[kt], acc0, 0, 0, 0);
            acc1 = __builtin_amdgcn_mfma_f32_16x16x32_bf16(a1, bfr[kt], acc1, 0, 0, 0);
        }
        {
            int cl = w * 16 + (l & 15);
#pragma unroll
            for (int r = 0; r < 4; ++r) {
                int m = (l >> 4) * 4 + r;
                res_sh[m * 68 + cl]        = oob ? NEG_INF : acc0[r] + bias;
                res_sh[(m + 16) * 68 + cl] = oob ? NEG_INF : acc1[r] + bias;
            }
        }
        __syncthreads();
        for (int i = tid; i < 32 * 64; i += 256) {
            int m = i >> 6, cl = i & 63;
            int col = blk * 64 + cl;
            if (col < VV) out[((size_t)m * TT + t) * VV + col] = res_sh[m * 68 + cl];
        }
        __syncthreads();
    }
}

extern "C" void kernel_launch(void* const* d_in, const int* in_sizes, int n_in,
                              void* d_out, int out_size, void* d_ws, size_t ws_size,
                              hipStream_t stream) {
    const float* fused  = (const float*)d_in[0];
    const int*   target = (const int*)d_in[1];
    const int*   tfm    = (const int*)d_in[2];
    const float* emb    = (const float*)d_in[3];
    const float* w_ih0  = (const float*)d_in[4];
    const float* w_hh0  = (const float*)d_in[5];
    const float* b_ih0  = (const float*)d_in[6];
    const float* b_hh0  = (const float*)d_in[7];
    const float* w_ih1  = (const float*)d_in[8];
    const float* w_hh1  = (const float*)d_in[9];
    const float* b_ih1  = (const float*)d_in[10];
    const float* b_hh1  = (const float*)d_in[11];
    const float* fc_w   = (const float*)d_in[12];
    const float* fc_b   = (const float*)d_in[13];
    float* out = (float*)d_out;

    float* ws = (float*)d_ws;
    float* h0buf = ws;
    float* h1buf = ws + 32768;
    float* c0 = ws + 65536;
    float* c1 = ws + 81920;
    int* tokbuf = (int*)(ws + 98304);
    float* xnorm = ws + 100352;
    unsigned* wmax = (unsigned*)(ws + 100384);
    unsigned long long* cand = (unsigned long long*)(ws + 100416);
    short* w_hi = (short*)(ws + 344640);
    short* h1b16 = (short*)(ws + 8158272);

    init_k<<<64, 256, 0, stream>>>(ws, fused);
    prep_k<<<NTILE, 256, 0, stream>>>(fc_w, w_hi, wmax);

    for (int t = 0; t < TT; ++t) {
        const float* h0prev = h0buf + ((t + 1) & 1) * 16384;
        float*       h0cur  = h0buf + (t & 1) * 16384;
        const float* h1prev = h1buf + ((t + 1) & 1) * 16384;
        float*       h1cur  = h1buf + (t & 1) * 16384;

        lstm_step<<<256, 256, 0, stream>>>(t, 0, emb, tokbuf,
                                           h0prev, h0cur, c0, w_ih0, w_hh0, b_ih0, b_hh0,
                                           nullptr);
        lstm_step<<<256, 256, 0, stream>>>(t, 1, h0cur, tokbuf,
                                           h1prev, h1cur, c1, w_ih1, w_hh1, b_ih1, b_hh1,
                                           h1b16 + (size_t)t * 16384);
        if (t < TT - 1) {
            fcarg<<<NTILE, 256, 0, stream>>>(t, tfm, h1cur, w_hi, fc_b, cand, xnorm, wmax);
            argmax_k<<<32, 256, 0, stream>>>(t, target, tfm, cand, h1cur, fc_w, fc_b,
                                             xnorm, wmax, tokbuf);
        }
    }
    logits_all<<<dim3(NTILE, 8), 256, 0, stream>>>(h1b16, w_hi, fc_b, out);
}

// Round 11
// 4884.213 us; speedup vs baseline: 2.9507x; 1.0381x over previous
//
#include <hip/hip_runtime.h>
#include <hip/hip_bf16.h>
#include <math.h>

#define TT 64
#define HH 512
#define VV 30522
#define START_TOK 101
#define NTILE 477      // ceil(30522/64)
#define KCAND 8

typedef __attribute__((ext_vector_type(8))) short short8v;
typedef __attribute__((ext_vector_type(4))) float f32x4;

__device__ inline short f2bf(float x) {
    union { float f; unsigned u; } v; v.f = x;
    unsigned r = v.u + 0x7FFFu + ((v.u >> 16) & 1u);   // RNE
    return (short)(r >> 16);
}
__device__ inline unsigned long long packkey(float v, int col) {
    unsigned u = __float_as_uint(v);
    unsigned key = (u & 0x80000000u) ? ~u : (u | 0x80000000u);
    return ((unsigned long long)key << 32) | (unsigned)col;
}
__device__ inline float keyval(unsigned long long k) {
    unsigned hi = (unsigned)(k >> 32);
    unsigned bits = (hi & 0x80000000u) ? (hi ^ 0x80000000u) : ~hi;
    return __uint_as_float(bits);
}

// ws layout (float units):
// h0[2][16384] @ 0 | h1[2][16384] @ 32768 | c0 @ 65536 | c1 @ 81920
// tokbuf int[64*32] @ 98304 | xnorm f32[32] @ 100352 | wmax u32 @ 100384
// cand u64[32*477*8] @ 100416 (244224 floats, ends 344640)
// w_hi bf16[30522*512] @ 344640 (7813632 floats, ends 8158272)
// h1b16 bf16[64][32][512] @ 8158272 (524288 floats) -> total ~34.7 MB

__global__ void init_k(float* ws, const float* __restrict__ fused) {
    int i = blockIdx.x * blockDim.x + threadIdx.x;
    if (i < 16384) {
        float f = fused[i];
        ws[16384 + i] = f;            // h0 parity-1 (t=0 reads prev = buf1)
        ws[32768 + 16384 + i] = f;    // h1 parity-1
        ws[65536 + i] = 0.f;          // c0
        ws[81920 + i] = 0.f;          // c1
    }
    if (i == 0) ((unsigned*)(ws + 100384))[0] = 0u;      // wmax (reset every call)
}

// fc_w fp32 -> bf16 (RNE, row-major) + global max column L2-norm
__global__ __launch_bounds__(256) void prep_k(const float* __restrict__ fc_w,
                                              short* __restrict__ w_hi,
                                              unsigned* __restrict__ wmax) {
    int r = blockIdx.x * 64 + (threadIdx.x >> 2);
    int seg = threadIdx.x & 3;
    if (r >= VV) return;
    const float* wp = fc_w + (size_t)r * HH + seg * 128;
    short* op = w_hi + (size_t)r * HH + seg * 128;
    float ss = 0.f;
#pragma unroll
    for (int c = 0; c < 16; ++c) {
        float4 x0 = *(const float4*)(wp + c * 8);
        float4 x1 = *(const float4*)(wp + c * 8 + 4);
        ss += x0.x*x0.x + x0.y*x0.y + x0.z*x0.z + x0.w*x0.w
            + x1.x*x1.x + x1.y*x1.y + x1.z*x1.z + x1.w*x1.w;
        short8v s;
        s[0]=f2bf(x0.x); s[1]=f2bf(x0.y); s[2]=f2bf(x0.z); s[3]=f2bf(x0.w);
        s[4]=f2bf(x1.x); s[5]=f2bf(x1.y); s[6]=f2bf(x1.z); s[7]=f2bf(x1.w);
        *(short8v*)(op + c * 8) = s;
    }
    ss += __shfl_xor(ss, 1); ss += __shfl_xor(ss, 2);
    if (seg == 0) atomicMax(wmax, __float_as_uint(sqrtf(ss)));
}

// One LSTM layer, one timestep (R2-proven). mode 0: x = emb[tokbuf]; mode 1: x = xsrc rows.
// h1b16out (nullable): bf16 archive of this step's h (for the batched logits GEMM).
__global__ __launch_bounds__(256) void lstm_step(
    int t, int mode,
    const float* __restrict__ xsrc,
    const int* __restrict__ tokbuf,
    const float* __restrict__ hprev,
    float* __restrict__ hout,
    float* __restrict__ cstate,
    const float* __restrict__ w_ih,
    const float* __restrict__ w_hh,
    const float* __restrict__ b_ih,
    const float* __restrict__ b_hh,
    short* __restrict__ h1b16out)
{
    __shared__ float in_lds[32 * 258];
    __shared__ float red[32 * 64];
    __shared__ float gate[4 * 64];
    __shared__ int tok_lds[32];

    const int tid = threadIdx.x;
    const int j = tid >> 5, b = tid & 31;
    const int u0 = blockIdx.x * 2;

    if (mode == 0 && tid < 32)
        tok_lds[tid] = (t == 0) ? START_TOK : tokbuf[t * 32 + tid];
    __syncthreads();

    float acc[8];
#pragma unroll
    for (int r = 0; r < 8; ++r) acc[r] = 0.f;
    int rowoff[8];
#pragma unroll
    for (int rl = 0; rl < 8; ++rl) {
        int gt = rl >> 1, ul = rl & 1;
        rowoff[rl] = (gt * 512 + u0 + ul) * 512;
    }

    for (int p = 0; p < 4; ++p) {
        const int koff = (p & 1) * 256;
        for (int i = tid; i < 32 * 128; i += 256) {
            int bb2 = i >> 7, k2 = (i & 127) * 2;
            const float* rp;
            if (p < 2) rp = (mode == 0) ? (xsrc + (size_t)tok_lds[bb2] * 512) : (xsrc + bb2 * 512);
            else       rp = hprev + bb2 * 512;
            float2 v = *(const float2*)(rp + koff + k2);
            *(float2*)&in_lds[bb2 * 258 + k2] = v;
        }
        __syncthreads();
        const float* wb = (p < 2) ? w_ih : w_hh;
#pragma unroll
        for (int m2 = 0; m2 < 8; ++m2) {
            int kl = j * 32 + m2 * 4;
            float2 x0 = *(const float2*)&in_lds[b * 258 + kl];
            float2 x1 = *(const float2*)&in_lds[b * 258 + kl + 2];
#pragma unroll
            for (int rl = 0; rl < 8; ++rl) {
                float4 w4 = *(const float4*)(wb + rowoff[rl] + koff + kl);
                acc[rl] += x0.x * w4.x + x0.y * w4.y + x1.x * w4.z + x1.y * w4.w;
            }
        }
        __syncthreads();
    }

#pragma unroll
    for (int rl = 0; rl < 8; ++rl) red[(b * 8 + rl) * 8 + j] = acc[rl];
    __syncthreads();

    {
        int b2 = tid >> 3, r2 = tid & 7;
        float s = 0.f;
#pragma unroll
        for (int jj = 0; jj < 8; ++jj) s += red[(b2 * 8 + r2) * 8 + jj];
        int gt = r2 >> 1, ul = r2 & 1;
        int rg = gt * 512 + u0 + ul;
        s += b_ih[rg] + b_hh[rg];
        gate[gt * 64 + ul * 32 + b2] = s;
    }
    __syncthreads();

    if (tid < 64) {
        int ul = tid >> 5, b3 = tid & 31;
        float gi = gate[0 * 64 + tid];
        float gf = gate[1 * 64 + tid];
        float gg = gate[2 * 64 + tid];
        float go = gate[3 * 64 + tid];
        float si = 1.f / (1.f + expf(-gi));
        float sf = 1.f / (1.f + expf(-gf));
        float so = 1.f / (1.f + expf(-go));
        float tg = tanhf(gg);
        int u = u0 + ul;
        float cold = cstate[b3 * 512 + u];
        float cn = sf * cold + si * tg;
        cstate[b3 * 512 + u] = cn;
        float h = so * tanhf(cn);
        hout[b3 * 512 + u] = h;
        if (h1b16out) h1b16out[b3 * 512 + u] = f2bf(h);
    }
}

// Candidate-only FC (non-TF steps): bf16 MFMA + margin candidates. No logit writes.
__global__ __launch_bounds__(256) void fcarg(
    int t,
    const int* __restrict__ tfm,
    const float* __restrict__ h1,     // [32][512] fp32
    const short* __restrict__ w_hi,   // [30522][512] bf16 row-major
    const float* __restrict__ fc_b,
    unsigned long long* __restrict__ cand,
    float* __restrict__ xnorm_g,
    const unsigned* __restrict__ wmax)
{
    if (tfm[t] > 0) return;   // teacher-forced: argmax not needed

    __shared__ short a_sh[32 * 512];
    __shared__ float res_sh[32 * 68];
    __shared__ float xnorm_sh[32];
    __shared__ float wmax_sh;
    __shared__ int cnt_sh[32];

    const int tid = threadIdx.x;
    const int blk = blockIdx.x;
    const float NEG_INF = -__builtin_inff();

    // Phase 1: h1 -> bf16 LDS (swizzled) + row norms
    {
        int row = tid >> 3, seg = tid & 7;
        const float* hp = h1 + row * 512 + seg * 64;
        float ss = 0.f;
#pragma unroll
        for (int c = 0; c < 8; ++c) {
            float4 x0 = *(const float4*)(hp + c * 8);
            float4 x1 = *(const float4*)(hp + c * 8 + 4);
            ss += x0.x*x0.x + x0.y*x0.y + x0.z*x0.z + x0.w*x0.w
                + x1.x*x1.x + x1.y*x1.y + x1.z*x1.z + x1.w*x1.w;
            short8v s;
            s[0]=f2bf(x0.x); s[1]=f2bf(x0.y); s[2]=f2bf(x0.z); s[3]=f2bf(x0.w);
            s[4]=f2bf(x1.x); s[5]=f2bf(x1.y); s[6]=f2bf(x1.z); s[7]=f2bf(x1.w);
            int kbase = seg * 64 + c * 8;
            int off = (row * 1024 + kbase * 2) ^ ((row & 7) << 4);
            *(short8v*)((char*)a_sh + off) = s;
        }
        ss += __shfl_xor(ss, 1); ss += __shfl_xor(ss, 2); ss += __shfl_xor(ss, 4);
        if (seg == 0) xnorm_sh[row] = sqrtf(ss);
        if (tid == 0) wmax_sh = __uint_as_float(*wmax);
    }
    __syncthreads();
    if (blk == 0 && tid < 32) xnorm_g[tid] = xnorm_sh[tid];

    // Phase 2: MFMA (row-major B fragment loads, R2-proven)
    const int w = tid >> 6, l = tid & 63;
    const int n0 = blk * 64 + w * 16;
    int bcol = n0 + (l & 15); if (bcol > VV - 1) bcol = VV - 1;
    const short* bp = w_hi + (size_t)bcol * HH + ((l >> 4) * 8);
    const int r0 = (l & 15), r1 = (l & 15) + 16;
    f32x4 acc0 = {0.f, 0.f, 0.f, 0.f}, acc1 = {0.f, 0.f, 0.f, 0.f};
#pragma unroll
    for (int kt = 0; kt < 16; ++kt) {
        int k2 = (kt * 32 + (l >> 4) * 8) * 2;
        short8v bfrag = *(const short8v*)(bp + kt * 32);
        short8v a0 = *(const short8v*)((char*)a_sh + ((r0 * 1024 + k2) ^ ((r0 & 7) << 4)));
        short8v a1 = *(const short8v*)((char*)a_sh + ((r1 * 1024 + k2) ^ ((r1 & 7) << 4)));
        acc0 = __builtin_amdgcn_mfma_f32_16x16x32_bf16(a0, bfrag, acc0, 0, 0, 0);
        acc1 = __builtin_amdgcn_mfma_f32_16x16x32_bf16(a1, bfrag, acc1, 0, 0, 0);
    }

    // Phase 3: bias + res LDS
    {
        float bias = fc_b[bcol];
        bool oob = (n0 + (l & 15)) >= VV;
        int cl = w * 16 + (l & 15);
#pragma unroll
        for (int r = 0; r < 4; ++r) {
            int m = (l >> 4) * 4 + r;
            res_sh[m * 68 + cl]        = oob ? NEG_INF : acc0[r] + bias;
            res_sh[(m + 16) * 68 + cl] = oob ? NEG_INF : acc1[r] + bias;
        }
    }
    __syncthreads();

    // Phase 4: per-row block top + margin candidates
    {
        int row = tid >> 3, sub = tid & 7;
        float bv = NEG_INF; int bc = 0x7FFFFFFF;
        for (int c = 0; c < 8; ++c) {
            float v = res_sh[row * 68 + sub * 8 + c];
            if (v > bv) { bv = v; bc = blk * 64 + sub * 8 + c; }
        }
#pragma unroll
        for (int d = 1; d < 8; d <<= 1) {
            float ov = __shfl_xor(bv, d);
            int oc = __shfl_xor(bc, d);
            if (ov > bv || (ov == bv && oc < bc)) { bv = ov; bc = oc; }
        }
        unsigned long long* slotp = cand + ((size_t)row * NTILE + blk) * KCAND;
        if (sub == 0) { slotp[0] = packkey(bv, bc); cnt_sh[row] = 1; }
        __syncthreads();
        float cthr = bv - xnorm_sh[row] * wmax_sh * (1.0f / 128.0f);
        for (int c = 0; c < 8; ++c) {
            float v = res_sh[row * 68 + sub * 8 + c];
            int col = blk * 64 + sub * 8 + c;
            if (v >= cthr && col != bc) {
                int idx = atomicAdd(&cnt_sh[row], 1);
                if (idx < KCAND) slotp[idx] = packkey(v, col);
            }
        }
        __syncthreads();
        if (sub == 0) {
            int n = cnt_sh[row]; if (n > KCAND) n = KCAND;
            for (int k = n; k < KCAND; ++k) slotp[k] = 0ull;
        }
    }
}

// Global candidate scan + exact fp32 rescore -> token for step t+1 (R2-proven)
__global__ __launch_bounds__(256) void argmax_k(
    int t,
    const int* __restrict__ target,
    const int* __restrict__ tfm,
    const unsigned long long* __restrict__ cand,
    const float* __restrict__ h1,
    const float* __restrict__ fc_w,
    const float* __restrict__ fc_b,
    const float* __restrict__ xnorm,
    const unsigned* __restrict__ wmax,
    int* __restrict__ tokbuf)
{
    const int r = blockIdx.x, tid = threadIdx.x;
    if (tfm[t] > 0) {
        if (tid == 0) tokbuf[(t + 1) * 32 + r] = target[r * TT + t + 1];
        return;
    }
    __shared__ unsigned long long red[256];
    __shared__ int list[32];
    __shared__ int lcnt;
    const int n = NTILE * KCAND;
    const unsigned long long* cp = cand + (size_t)r * n;

    unsigned long long m = 0ull;
    for (int i = tid; i < n; i += 256) { unsigned long long k = cp[i]; m = (k > m) ? k : m; }
    red[tid] = m; __syncthreads();
    for (int s = 128; s > 0; s >>= 1) {
        if (tid < s) { unsigned long long o = red[tid + s]; if (o > red[tid]) red[tid] = o; }
        __syncthreads();
    }
    float Mv = keyval(red[0]);
    float thr = Mv - xnorm[r] * __uint_as_float(*wmax) * (1.0f / 128.0f);
    if (tid == 0) lcnt = 0;
    __syncthreads();
    for (int i = tid; i < n; i += 256) {
        unsigned long long k = cp[i];
        if (!k) continue;
        float v = keyval(k);
        if (v >= thr) {
            int idx = atomicAdd(&lcnt, 1);
            if (idx < 32) list[idx] = (int)(k & 0xFFFFFFFFull);
        }
    }
    __syncthreads();
    int nc = lcnt < 32 ? lcnt : 32;

    if (tid < 64) {
        float bv = -__builtin_inff(); int bc = 0x7FFFFFFF;
        for (int jc = 0; jc < nc; ++jc) {
            int col = list[jc];
            const float* wp = fc_w + (size_t)col * HH + tid * 8;
            const float* xp = h1 + r * 512 + tid * 8;
            float4 a0 = *(const float4*)wp, a1 = *(const float4*)(wp + 4);
            float4 b0 = *(const float4*)xp, b1 = *(const float4*)(xp + 4);
            float s = a0.x*b0.x + a0.y*b0.y + a0.z*b0.z + a0.w*b0.w
                    + a1.x*b1.x + a1.y*b1.y + a1.z*b1.z + a1.w*b1.w;
#pragma unroll
            for (int d = 1; d < 64; d <<= 1) s += __shfl_xor(s, d);
            s += fc_b[col];
            if (s > bv || (s == bv && col < bc)) { bv = s; bc = col; }
        }
        if (tid == 0) tokbuf[(t + 1) * 32 + r] = bc;
    }
}

// Batched logits GEMM: [2048 x 30522] = h1b16 x w_hi^T + fc_b, written once.
// R11: res aliased into a_sh (LDS 41.5->33 KB, 4 blocks/CU) + non-temporal out
// stores (write-once data; keep w_hi L2-resident -> FETCH 134MB -> ~40MB).
__global__ __launch_bounds__(256) void logits_all(
    const short* __restrict__ h1b16,   // [64][32][512] bf16
    const short* __restrict__ w_hi,    // [30522][512] bf16 row-major
    const float* __restrict__ fc_b,
    float* __restrict__ out)
{
    __shared__ short a_sh[32 * 512];                 // 32 KB; res aliased below
    float* res_sh = (float*)a_sh;                    // 32*68 floats = 8.7 KB alias
    const int tid = threadIdx.x;
    const int blk = blockIdx.x;        // col tile
    const int tg  = blockIdx.y;        // 8 timesteps per group
    const float NEG_INF = -__builtin_inff();

    const int w = tid >> 6, l = tid & 63;
    const int n0 = blk * 64 + w * 16;
    int bcol = n0 + (l & 15); if (bcol > VV - 1) bcol = VV - 1;
    const bool oob = (n0 + (l & 15)) >= VV;
    const float bias = fc_b[bcol];
    const short* bp = w_hi + (size_t)bcol * HH + ((l >> 4) * 8);
    short8v bfr[16];
#pragma unroll
    for (int kt = 0; kt < 16; ++kt) bfr[kt] = *(const short8v*)(bp + kt * 32);

    const int r0 = (l & 15), r1 = (l & 15) + 16;
    const int srow = tid >> 3, sseg = tid & 7;

    for (int ts = 0; ts < 8; ++ts) {
        const int t = tg * 8 + ts;
        const short* hp = h1b16 + t * 16384 + srow * 512 + sseg * 64;
#pragma unroll
        for (int c = 0; c < 8; ++c) {
            short8v v = *(const short8v*)(hp + c * 8);
            int k = sseg * 64 + c * 8;
            int off = (srow * 1024 + k * 2) ^ ((srow & 7) << 4);
            *(short8v*)((char*)a_sh + off) = v;
        }
        __syncthreads();

        f32x4 acc0 = {0.f,0.f,0.f,0.f}, acc1 = {0.f,0.f,0.f,0.f};
#pragma unroll
        for (int kt = 0; kt < 16; ++kt) {
            int k2 = (kt * 32 + (l >> 4) * 8) * 2;
            short8v a0 = *(const short8v*)((char*)a_sh + ((r0 * 1024 + k2) ^ ((r0 & 7) << 4)));
            short8v a1 = *(const short8v*)((char*)a_sh + ((r1 * 1024 + k2) ^ ((r1 & 7) << 4)));
            acc0 = __builtin_amdgcn_mfma_f32_16x16x32_bf16(a0, bfr[kt], acc0, 0, 0, 0);
            acc1 = __builtin_amdgcn_mfma_f32_16x16x32_bf16(a1, bfr[kt], acc1, 0, 0, 0);
        }
        __syncthreads();   // NEW: all waves done reading a_sh before res alias writes
        {
            int cl = w * 16 + (l & 15);
#pragma unroll
            for (int r = 0; r < 4; ++r) {
                int m = (l >> 4) * 4 + r;
                res_sh[m * 68 + cl]        = oob ? NEG_INF : acc0[r] + bias;
                res_sh[(m + 16) * 68 + cl] = oob ? NEG_INF : acc1[r] + bias;
            }
        }
        __syncthreads();
        for (int i = tid; i < 32 * 64; i += 256) {
            int m = i >> 6, cl = i & 63;
            int col = blk * 64 + cl;
            if (col < VV)
                __builtin_nontemporal_store(res_sh[m * 68 + cl],
                                            &out[((size_t)m * TT + t) * VV + col]);
        }
        __syncthreads();   // res alias dead before next ts restages a_sh
    }
}

extern "C" void kernel_launch(void* const* d_in, const int* in_sizes, int n_in,
                              void* d_out, int out_size, void* d_ws, size_t ws_size,
                              hipStream_t stream) {
    const float* fused  = (const float*)d_in[0];
    const int*   target = (const int*)d_in[1];
    const int*   tfm    = (const int*)d_in[2];
    const float* emb    = (const float*)d_in[3];
    const float* w_ih0  = (const float*)d_in[4];
    const float* w_hh0  = (const float*)d_in[5];
    const float* b_ih0  = (const float*)d_in[6];
    const float* b_hh0  = (const float*)d_in[7];
    const float* w_ih1  = (const float*)d_in[8];
    const float* w_hh1  = (const float*)d_in[9];
    const float* b_ih1  = (const float*)d_in[10];
    const float* b_hh1  = (const float*)d_in[11];
    const float* fc_w   = (const float*)d_in[12];
    const float* fc_b   = (const float*)d_in[13];
    float* out = (float*)d_out;

    float* ws = (float*)d_ws;
    float* h0buf = ws;
    float* h1buf = ws + 32768;
    float* c0 = ws + 65536;
    float* c1 = ws + 81920;
    int* tokbuf = (int*)(ws + 98304);
    float* xnorm = ws + 100352;
    unsigned* wmax = (unsigned*)(ws + 100384);
    unsigned long long* cand = (unsigned long long*)(ws + 100416);
    short* w_hi = (short*)(ws + 344640);
    short* h1b16 = (short*)(ws + 8158272);

    init_k<<<64, 256, 0, stream>>>(ws, fused);
    prep_k<<<NTILE, 256, 0, stream>>>(fc_w, w_hi, wmax);

    for (int t = 0; t < TT; ++t) {
        const float* h0prev = h0buf + ((t + 1) & 1) * 16384;
        float*       h0cur  = h0buf + (t & 1) * 16384;
        const float* h1prev = h1buf + ((t + 1) & 1) * 16384;
        float*       h1cur  = h1buf + (t & 1) * 16384;

        lstm_step<<<256, 256, 0, stream>>>(t, 0, emb, tokbuf,
                                           h0prev, h0cur, c0, w_ih0, w_hh0, b_ih0, b_hh0,
                                           nullptr);
        lstm_step<<<256, 256, 0, stream>>>(t, 1, h0cur, tokbuf,
                                           h1prev, h1cur, c1, w_ih1, w_hh1, b_ih1, b_hh1,
                                           h1b16 + (size_t)t * 16384);
        if (t < TT - 1) {
            fcarg<<<NTILE, 256, 0, stream>>>(t, tfm, h1cur, w_hi, fc_b, cand, xnorm, wmax);
            argmax_k<<<32, 256, 0, stream>>>(t, target, tfm, cand, h1cur, fc_w, fc_b,
                                             xnorm, wmax, tokbuf);
        }
    }
    logits_all<<<dim3(NTILE, 8), 256, 0, stream>>>(h1b16, w_hi, fc_b, out);
}

// Round 13
// 4844.518 us; speedup vs baseline: 2.9748x; 1.0082x over previous
//
#include <hip/hip_runtime.h>
#include <hip/hip_bf16.h>
#include <math.h>

#define TT 64
#define HH 512
#define VV 30522
#define START_TOK 101
#define NTILE 477      // ceil(30522/64)
#define KCAND 8
#define TPG 32         // timesteps per logits block

typedef __attribute__((ext_vector_type(8))) short short8v;
typedef __attribute__((ext_vector_type(4))) float f32x4;

__device__ inline short f2bf(float x) {
    union { float f; unsigned u; } v; v.f = x;
    unsigned r = v.u + 0x7FFFu + ((v.u >> 16) & 1u);   // RNE
    return (short)(r >> 16);
}
__device__ inline unsigned long long packkey(float v, int col) {
    unsigned u = __float_as_uint(v);
    unsigned key = (u & 0x80000000u) ? ~u : (u | 0x80000000u);
    return ((unsigned long long)key << 32) | (unsigned)col;
}
__device__ inline float keyval(unsigned long long k) {
    unsigned hi = (unsigned)(k >> 32);
    unsigned bits = (hi & 0x80000000u) ? (hi ^ 0x80000000u) : ~hi;
    return __uint_as_float(bits);
}
// unified LDS swizzle (involution, bits 4-6): slot ^= row ^ kseg. Makes both
// staging writes (consecutive lanes = same row, seg 0..7) and MFMA fragment
// reads (lanes = rows 0..15 at fixed kt) hit distinct bank groups.
__device__ __forceinline__ int swz(int base) {
    return base ^ ((((base >> 10) ^ (base >> 7)) & 7) << 4);
}

// ws layout (float units):
// h0[2][16384] @ 0 | h1[2][16384] @ 32768 | c0 @ 65536 | c1 @ 81920
// tokbuf int[64*32] @ 98304 | xnorm f32[32] @ 100352 | wmax u32 @ 100384
// cand u64[32*477*8] @ 100416 (244224 floats, ends 344640)
// w_hi bf16[30522*512] @ 344640 | h1b16 bf16[64][32][512] @ 8158272

__global__ void init_k(float* ws, const float* __restrict__ fused) {
    int i = blockIdx.x * blockDim.x + threadIdx.x;
    if (i < 16384) {
        float f = fused[i];
        ws[16384 + i] = f;            // h0 parity-1 (t=0 reads prev = buf1)
        ws[32768 + 16384 + i] = f;    // h1 parity-1
        ws[65536 + i] = 0.f;          // c0
        ws[81920 + i] = 0.f;          // c1
    }
    if (i == 0) ((unsigned*)(ws + 100384))[0] = 0u;      // wmax (reset every call)
}

// fc_w fp32 -> bf16 (RNE, row-major) + global max column L2-norm
__global__ __launch_bounds__(256) void prep_k(const float* __restrict__ fc_w,
                                              short* __restrict__ w_hi,
                                              unsigned* __restrict__ wmax) {
    int r = blockIdx.x * 64 + (threadIdx.x >> 2);
    int seg = threadIdx.x & 3;
    if (r >= VV) return;
    const float* wp = fc_w + (size_t)r * HH + seg * 128;
    short* op = w_hi + (size_t)r * HH + seg * 128;
    float ss = 0.f;
#pragma unroll
    for (int c = 0; c < 16; ++c) {
        float4 x0 = *(const float4*)(wp + c * 8);
        float4 x1 = *(const float4*)(wp + c * 8 + 4);
        ss += x0.x*x0.x + x0.y*x0.y + x0.z*x0.z + x0.w*x0.w
            + x1.x*x1.x + x1.y*x1.y + x1.z*x1.z + x1.w*x1.w;
        short8v s;
        s[0]=f2bf(x0.x); s[1]=f2bf(x0.y); s[2]=f2bf(x0.z); s[3]=f2bf(x0.w);
        s[4]=f2bf(x1.x); s[5]=f2bf(x1.y); s[6]=f2bf(x1.z); s[7]=f2bf(x1.w);
        *(short8v*)(op + c * 8) = s;
    }
    ss += __shfl_xor(ss, 1); ss += __shfl_xor(ss, 2);
    if (seg == 0) atomicMax(wmax, __float_as_uint(sqrtf(ss)));
}

// One LSTM layer, one timestep (R2-proven). mode 0: x = emb[tokbuf]; mode 1: x = xsrc rows.
__global__ __launch_bounds__(256) void lstm_step(
    int t, int mode,
    const float* __restrict__ xsrc,
    const int* __restrict__ tokbuf,
    const float* __restrict__ hprev,
    float* __restrict__ hout,
    float* __restrict__ cstate,
    const float* __restrict__ w_ih,
    const float* __restrict__ w_hh,
    const float* __restrict__ b_ih,
    const float* __restrict__ b_hh,
    short* __restrict__ h1b16out)
{
    __shared__ float in_lds[32 * 258];
    __shared__ float red[32 * 64];
    __shared__ float gate[4 * 64];
    __shared__ int tok_lds[32];

    const int tid = threadIdx.x;
    const int j = tid >> 5, b = tid & 31;
    const int u0 = blockIdx.x * 2;

    if (mode == 0 && tid < 32)
        tok_lds[tid] = (t == 0) ? START_TOK : tokbuf[t * 32 + tid];
    __syncthreads();

    float acc[8];
#pragma unroll
    for (int r = 0; r < 8; ++r) acc[r] = 0.f;
    int rowoff[8];
#pragma unroll
    for (int rl = 0; rl < 8; ++rl) {
        int gt = rl >> 1, ul = rl & 1;
        rowoff[rl] = (gt * 512 + u0 + ul) * 512;
    }

    for (int p = 0; p < 4; ++p) {
        const int koff = (p & 1) * 256;
        for (int i = tid; i < 32 * 128; i += 256) {
            int bb2 = i >> 7, k2 = (i & 127) * 2;
            const float* rp;
            if (p < 2) rp = (mode == 0) ? (xsrc + (size_t)tok_lds[bb2] * 512) : (xsrc + bb2 * 512);
            else       rp = hprev + bb2 * 512;
            float2 v = *(const float2*)(rp + koff + k2);
            *(float2*)&in_lds[bb2 * 258 + k2] = v;
        }
        __syncthreads();
        const float* wb = (p < 2) ? w_ih : w_hh;
#pragma unroll
        for (int m2 = 0; m2 < 8; ++m2) {
            int kl = j * 32 + m2 * 4;
            float2 x0 = *(const float2*)&in_lds[b * 258 + kl];
            float2 x1 = *(const float2*)&in_lds[b * 258 + kl + 2];
#pragma unroll
            for (int rl = 0; rl < 8; ++rl) {
                float4 w4 = *(const float4*)(wb + rowoff[rl] + koff + kl);
                acc[rl] += x0.x * w4.x + x0.y * w4.y + x1.x * w4.z + x1.y * w4.w;
            }
        }
        __syncthreads();
    }

#pragma unroll
    for (int rl = 0; rl < 8; ++rl) red[(b * 8 + rl) * 8 + j] = acc[rl];
    __syncthreads();

    {
        int b2 = tid >> 3, r2 = tid & 7;
        float s = 0.f;
#pragma unroll
        for (int jj = 0; jj < 8; ++jj) s += red[(b2 * 8 + r2) * 8 + jj];
        int gt = r2 >> 1, ul = r2 & 1;
        int rg = gt * 512 + u0 + ul;
        s += b_ih[rg] + b_hh[rg];
        gate[gt * 64 + ul * 32 + b2] = s;
    }
    __syncthreads();

    if (tid < 64) {
        int ul = tid >> 5, b3 = tid & 31;
        float gi = gate[0 * 64 + tid];
        float gf = gate[1 * 64 + tid];
        float gg = gate[2 * 64 + tid];
        float go = gate[3 * 64 + tid];
        float si = 1.f / (1.f + expf(-gi));
        float sf = 1.f / (1.f + expf(-gf));
        float so = 1.f / (1.f + expf(-go));
        float tg = tanhf(gg);
        int u = u0 + ul;
        float cold = cstate[b3 * 512 + u];
        float cn = sf * cold + si * tg;
        cstate[b3 * 512 + u] = cn;
        float h = so * tanhf(cn);
        hout[b3 * 512 + u] = h;
        if (h1b16out) h1b16out[b3 * 512 + u] = f2bf(h);
    }
}

// Candidate-only FC (non-TF steps): bf16 MFMA + margin candidates. No logit writes.
__global__ __launch_bounds__(256) void fcarg(
    int t,
    const int* __restrict__ tfm,
    const float* __restrict__ h1,     // [32][512] fp32
    const short* __restrict__ w_hi,   // [30522][512] bf16 row-major
    const float* __restrict__ fc_b,
    unsigned long long* __restrict__ cand,
    float* __restrict__ xnorm_g,
    const unsigned* __restrict__ wmax)
{
    if (tfm[t] > 0) return;   // teacher-forced: argmax not needed

    __shared__ short a_sh[32 * 512];
    __shared__ float res_sh[32 * 68];
    __shared__ float xnorm_sh[32];
    __shared__ float wmax_sh;
    __shared__ int cnt_sh[32];

    const int tid = threadIdx.x;
    const int blk = blockIdx.x;
    const float NEG_INF = -__builtin_inff();

    // Phase 1: h1 -> bf16 LDS (unified swizzle) + row norms
    {
        int row = tid >> 3, seg = tid & 7;
        const float* hp = h1 + row * 512 + seg * 64;
        float ss = 0.f;
#pragma unroll
        for (int c = 0; c < 8; ++c) {
            float4 x0 = *(const float4*)(hp + c * 8);
            float4 x1 = *(const float4*)(hp + c * 8 + 4);
            ss += x0.x*x0.x + x0.y*x0.y + x0.z*x0.z + x0.w*x0.w
                + x1.x*x1.x + x1.y*x1.y + x1.z*x1.z + x1.w*x1.w;
            short8v s;
            s[0]=f2bf(x0.x); s[1]=f2bf(x0.y); s[2]=f2bf(x0.z); s[3]=f2bf(x0.w);
            s[4]=f2bf(x1.x); s[5]=f2bf(x1.y); s[6]=f2bf(x1.z); s[7]=f2bf(x1.w);
            int kbase = seg * 64 + c * 8;
            *(short8v*)((char*)a_sh + swz(row * 1024 + kbase * 2)) = s;
        }
        ss += __shfl_xor(ss, 1); ss += __shfl_xor(ss, 2); ss += __shfl_xor(ss, 4);
        if (seg == 0) xnorm_sh[row] = sqrtf(ss);
        if (tid == 0) wmax_sh = __uint_as_float(*wmax);
    }
    __syncthreads();
    if (blk == 0 && tid < 32) xnorm_g[tid] = xnorm_sh[tid];

    // Phase 2: MFMA
    const int w = tid >> 6, l = tid & 63;
    const int n0 = blk * 64 + w * 16;
    int bcol = n0 + (l & 15); if (bcol > VV - 1) bcol = VV - 1;
    const short* bp = w_hi + (size_t)bcol * HH + ((l >> 4) * 8);
    const int r0 = (l & 15), r1 = (l & 15) + 16;
    f32x4 acc0 = {0.f, 0.f, 0.f, 0.f}, acc1 = {0.f, 0.f, 0.f, 0.f};
#pragma unroll
    for (int kt = 0; kt < 16; ++kt) {
        int kb = (kt * 32 + (l >> 4) * 8) * 2;
        short8v bfrag = *(const short8v*)(bp + kt * 32);
        short8v a0 = *(const short8v*)((char*)a_sh + swz(r0 * 1024 + kb));
        short8v a1 = *(const short8v*)((char*)a_sh + swz(r1 * 1024 + kb));
        acc0 = __builtin_amdgcn_mfma_f32_16x16x32_bf16(a0, bfrag, acc0, 0, 0, 0);
        acc1 = __builtin_amdgcn_mfma_f32_16x16x32_bf16(a1, bfrag, acc1, 0, 0, 0);
    }

    // Phase 3: bias + res LDS
    {
        float bias = fc_b[bcol];
        bool oob = (n0 + (l & 15)) >= VV;
        int cl = w * 16 + (l & 15);
#pragma unroll
        for (int r = 0; r < 4; ++r) {
            int m = (l >> 4) * 4 + r;
            res_sh[m * 68 + cl]        = oob ? NEG_INF : acc0[r] + bias;
            res_sh[(m + 16) * 68 + cl] = oob ? NEG_INF : acc1[r] + bias;
        }
    }
    __syncthreads();

    // Phase 4: per-row block top + margin candidates
    {
        int row = tid >> 3, sub = tid & 7;
        float bv = NEG_INF; int bc = 0x7FFFFFFF;
        for (int c = 0; c < 8; ++c) {
            float v = res_sh[row * 68 + sub * 8 + c];
            if (v > bv) { bv = v; bc = blk * 64 + sub * 8 + c; }
        }
#pragma unroll
        for (int d = 1; d < 8; d <<= 1) {
            float ov = __shfl_xor(bv, d);
            int oc = __shfl_xor(bc, d);
            if (ov > bv || (ov == bv && oc < bc)) { bv = ov; bc = oc; }
        }
        unsigned long long* slotp = cand + ((size_t)row * NTILE + blk) * KCAND;
        if (sub == 0) { slotp[0] = packkey(bv, bc); cnt_sh[row] = 1; }
        __syncthreads();
        float cthr = bv - xnorm_sh[row] * wmax_sh * (1.0f / 128.0f);
        for (int c = 0; c < 8; ++c) {
            float v = res_sh[row * 68 + sub * 8 + c];
            int col = blk * 64 + sub * 8 + c;
            if (v >= cthr && col != bc) {
                int idx = atomicAdd(&cnt_sh[row], 1);
                if (idx < KCAND) slotp[idx] = packkey(v, col);
            }
        }
        __syncthreads();
        if (sub == 0) {
            int n = cnt_sh[row]; if (n > KCAND) n = KCAND;
            for (int k = n; k < KCAND; ++k) slotp[k] = 0ull;
        }
    }
}

// Global candidate scan + exact fp32 rescore -> token for step t+1 (R2-proven;
// reads cand across the dispatch boundary — XCD-coherence safe per G16).
__global__ __launch_bounds__(256) void argmax_k(
    int t,
    const int* __restrict__ target,
    const int* __restrict__ tfm,
    const unsigned long long* __restrict__ cand,
    const float* __restrict__ h1,
    const float* __restrict__ fc_w,
    const float* __restrict__ fc_b,
    const float* __restrict__ xnorm,
    const unsigned* __restrict__ wmax,
    int* __restrict__ tokbuf)
{
    const int r = blockIdx.x, tid = threadIdx.x;
    if (tfm[t] > 0) {
        if (tid == 0) tokbuf[(t + 1) * 32 + r] = target[r * TT + t + 1];
        return;
    }
    __shared__ unsigned long long red[256];
    __shared__ int list[32];
    __shared__ int lcnt;
    const int n = NTILE * KCAND;
    const unsigned long long* cp = cand + (size_t)r * n;

    unsigned long long m = 0ull;
    for (int i = tid; i < n; i += 256) { unsigned long long k = cp[i]; m = (k > m) ? k : m; }
    red[tid] = m; __syncthreads();
    for (int s = 128; s > 0; s >>= 1) {
        if (tid < s) { unsigned long long o = red[tid + s]; if (o > red[tid]) red[tid] = o; }
        __syncthreads();
    }
    float Mv = keyval(red[0]);
    float thr = Mv - xnorm[r] * __uint_as_float(*wmax) * (1.0f / 128.0f);
    if (tid == 0) lcnt = 0;
    __syncthreads();
    for (int i = tid; i < n; i += 256) {
        unsigned long long k = cp[i];
        if (!k) continue;
        float v = keyval(k);
        if (v >= thr) {
            int idx = atomicAdd(&lcnt, 1);
            if (idx < 32) list[idx] = (int)(k & 0xFFFFFFFFull);
        }
    }
    __syncthreads();
    int nc = lcnt < 32 ? lcnt : 32;

    if (tid < 64) {
        float bv = -__builtin_inff(); int bc = 0x7FFFFFFF;
        for (int jc = 0; jc < nc; ++jc) {
            int col = list[jc];
            const float* wp = fc_w + (size_t)col * HH + tid * 8;
            const float* xp = h1 + r * 512 + tid * 8;
            float4 a0 = *(const float4*)wp, a1 = *(const float4*)(wp + 4);
            float4 b0 = *(const float4*)xp, b1 = *(const float4*)(xp + 4);
            float s = a0.x*b0.x + a0.y*b0.y + a0.z*b0.z + a0.w*b0.w
                    + a1.x*b1.x + a1.y*b1.y + a1.z*b1.z + a1.w*b1.w;
#pragma unroll
            for (int d = 1; d < 64; d <<= 1) s += __shfl_xor(s, d);
            s += fc_b[col];
            if (s > bv || (s == bv && col < bc)) { bv = s; bc = col; }
        }
        if (tid == 0) tokbuf[(t + 1) * 32 + r] = bc;
    }
}

// Batched logits GEMM: [2048 x 30522] = h1b16 x w_hi^T + fc_b.
// TPG=32 (w_hi read 2x not 8x), unified swizzle, res alias, NT stores.
__global__ __launch_bounds__(256) void logits_all(
    const short* __restrict__ h1b16,   // [64][32][512] bf16
    const short* __restrict__ w_hi,    // [30522][512] bf16 row-major
    const float* __restrict__ fc_b,
    float* __restrict__ out)
{
    __shared__ short a_sh[32 * 512];
    float* res_sh = (float*)a_sh;      // alias; guarded by barriers
    const int tid = threadIdx.x;
    const int blk = blockIdx.x;        // col tile
    const int tg  = blockIdx.y;        // TT/TPG groups
    const float NEG_INF = -__builtin_inff();

    const int w = tid >> 6, l = tid & 63;
    const int n0 = blk * 64 + w * 16;
    int bcol = n0 + (l & 15); if (bcol > VV - 1) bcol = VV - 1;
    const bool oob = (n0 + (l & 15)) >= VV;
    const float bias = fc_b[bcol];
    const short* bp = w_hi + (size_t)bcol * HH + ((l >> 4) * 8);
    short8v bfr[16];
#pragma unroll
    for (int kt = 0; kt < 16; ++kt) bfr[kt] = *(const short8v*)(bp + kt * 32);

    const int r0 = (l & 15), r1 = (l & 15) + 16;
    const int srow = tid >> 3, sseg = tid & 7;

    for (int ts = 0; ts < TPG; ++ts) {
        const int t = tg * TPG + ts;
        const short* hp = h1b16 + t * 16384 + srow * 512 + sseg * 64;
#pragma unroll
        for (int c = 0; c < 8; ++c) {
            short8v v = *(const short8v*)(hp + c * 8);
            int kbase = sseg * 64 + c * 8;
            *(short8v*)((char*)a_sh + swz(srow * 1024 + kbase * 2)) = v;
        }
        __syncthreads();

        f32x4 acc0 = {0.f,0.f,0.f,0.f}, acc1 = {0.f,0.f,0.f,0.f};
#pragma unroll
        for (int kt = 0; kt < 16; ++kt) {
            int kb = (kt * 32 + (l >> 4) * 8) * 2;
            short8v a0 = *(const short8v*)((char*)a_sh + swz(r0 * 1024 + kb));
            short8v a1 = *(const short8v*)((char*)a_sh + swz(r1 * 1024 + kb));
            acc0 = __builtin_amdgcn_mfma_f32_16x16x32_bf16(a0, bfr[kt], acc0, 0, 0, 0);
            acc1 = __builtin_amdgcn_mfma_f32_16x16x32_bf16(a1, bfr[kt], acc1, 0, 0, 0);
        }
        __syncthreads();   // a_sh reads done before res alias writes
        {
            int cl = w * 16 + (l & 15);
#pragma unroll
            for (int r = 0; r < 4; ++r) {
                int m = (l >> 4) * 4 + r;
                res_sh[m * 68 + cl]        = oob ? NEG_INF : acc0[r] + bias;
                res_sh[(m + 16) * 68 + cl] = oob ? NEG_INF : acc1[r] + bias;
            }
        }
        __syncthreads();
        for (int i = tid; i < 32 * 64; i += 256) {
            int m = i >> 6, cl = i & 63;
            int col = blk * 64 + cl;
            if (col < VV)
                __builtin_nontemporal_store(res_sh[m * 68 + cl],
                                            &out[((size_t)m * TT + t) * VV + col]);
        }
        __syncthreads();   // res alias dead before next ts restages a_sh
    }
}

extern "C" void kernel_launch(void* const* d_in, const int* in_sizes, int n_in,
                              void* d_out, int out_size, void* d_ws, size_t ws_size,
                              hipStream_t stream) {
    const float* fused  = (const float*)d_in[0];
    const int*   target = (const int*)d_in[1];
    const int*   tfm    = (const int*)d_in[2];
    const float* emb    = (const float*)d_in[3];
    const float* w_ih0  = (const float*)d_in[4];
    const float* w_hh0  = (const float*)d_in[5];
    const float* b_ih0  = (const float*)d_in[6];
    const float* b_hh0  = (const float*)d_in[7];
    const float* w_ih1  = (const float*)d_in[8];
    const float* w_hh1  = (const float*)d_in[9];
    const float* b_ih1  = (const float*)d_in[10];
    const float* b_hh1  = (const float*)d_in[11];
    const float* fc_w   = (const float*)d_in[12];
    const float* fc_b   = (const float*)d_in[13];
    float* out = (float*)d_out;

    float* ws = (float*)d_ws;
    float* h0buf = ws;
    float* h1buf = ws + 32768;
    float* c0 = ws + 65536;
    float* c1 = ws + 81920;
    int* tokbuf = (int*)(ws + 98304);
    float* xnorm = ws + 100352;
    unsigned* wmax = (unsigned*)(ws + 100384);
    unsigned long long* cand = (unsigned long long*)(ws + 100416);
    short* w_hi = (short*)(ws + 344640);
    short* h1b16 = (short*)(ws + 8158272);

    init_k<<<64, 256, 0, stream>>>(ws, fused);
    prep_k<<<NTILE, 256, 0, stream>>>(fc_w, w_hi, wmax);

    for (int t = 0; t < TT; ++t) {
        const float* h0prev = h0buf + ((t + 1) & 1) * 16384;
        float*       h0cur  = h0buf + (t & 1) * 16384;
        const float* h1prev = h1buf + ((t + 1) & 1) * 16384;
        float*       h1cur  = h1buf + (t & 1) * 16384;

        lstm_step<<<256, 256, 0, stream>>>(t, 0, emb, tokbuf,
                                           h0prev, h0cur, c0, w_ih0, w_hh0, b_ih0, b_hh0,
                                           nullptr);
        lstm_step<<<256, 256, 0, stream>>>(t, 1, h0cur, tokbuf,
                                           h1prev, h1cur, c1, w_ih1, w_hh1, b_ih1, b_hh1,
                                           h1b16 + (size_t)t * 16384);
        if (t < TT - 1) {
            fcarg<<<NTILE, 256, 0, stream>>>(t, tfm, h1cur, w_hi, fc_b, cand, xnorm, wmax);
            argmax_k<<<32, 256, 0, stream>>>(t, target, tfm, cand, h1cur, fc_w, fc_b,
                                             xnorm, wmax, tokbuf);
        }
    }
    logits_all<<<dim3(NTILE, TT / TPG), 256, 0, stream>>>(h1b16, w_hi, fc_b, out);
}